// Round 5
// baseline (143.551 us; speedup 1.0000x reference)
//
#include <hip/hip_runtime.h>

#define B_ 8
#define A_ 49104
#define C_ 20
#define M_ 32
#define N_ 16
#define AC_ (A_ * C_)     // 982080
#define APB_ 64           // anchors per block (fused kernel)
#define NB_ 768           // blocks = ceil(A/64)
#define TPB_ 320          // 5 waves; 64 anchors * 5 float4-chunks = 320 cls tasks

// Workspace: regpart double[B][NB] @0 (49152 B), clspart double[B][NB] @49152,
//            pospart int[B][NB] @98304. 'assigned' lives in LDS only.

__device__ __forceinline__ float cls_term(float e, float p, float alpha) {
    const float pc = fminf(fmaxf(p, 1e-4f), 1.0f - 1e-4f);
    const float ec = fminf(fmaxf(e, 1e-4f), 1.0f - 1e-4f);
    const float bce = -(ec * __logf(pc) + (1.0f - ec) * __logf(1.0f - pc));
    const float df = fabsf(ec - pc);
    return alpha * df * df * bce;
}

// Fused assign + cls, software-pipelined: ALL 16 global float4 loads for the
// cls pass are issued at kernel entry (independent, unconditional) so their
// latency hides under LDS staging + the assign loop. The per-batch 'assigned'
// gate is applied as a multiply-mask, not a branch, so no load sits behind
// divergent control flow.
__global__ __launch_bounds__(TPB_) void k_main(
        const float* __restrict__ anchors,        // [A,4]
        const float* __restrict__ regress,        // [B,A,4]
        const float* __restrict__ cls,            // [B,A,C]
        const float* __restrict__ ema,            // [B,A,C]
        const float* __restrict__ ema_classes,    // [B,M]
        const float* __restrict__ ema_bboxes,     // [B,M,4]
        const int*   __restrict__ ema_counts,     // [B]
        const float* __restrict__ annotations,    // [B,N,5]
        double* __restrict__ regpart,             // [B,NB]
        double* __restrict__ clspart,             // [B,NB]
        int* __restrict__ pospart)                // [B,NB]
{
    const int tid = threadIdx.x;
    const int a0 = blockIdx.x * APB_;

    // ---- phase 0: issue cls-pass loads NOW (consumed in phase 3) ----
    const int al3 = tid / 5;                   // anchor-local for cls pass
    const int ch  = tid % 5;                   // float4 chunk within C=20
    const int a3  = a0 + al3;
    const bool act3 = (a3 < A_);
    float4 e[B_], p[B_];
    if (act3) {
        const size_t cell = (size_t)a3 * C_ + ch * 4;
#pragma unroll
        for (int b = 0; b < B_; ++b) {
            e[b] = *reinterpret_cast<const float4*>(ema + (size_t)b * AC_ + cell);
            p[b] = *reinterpret_cast<const float4*>(cls + (size_t)b * AC_ + cell);
        }
    }

    __shared__ float4 sbox[B_][M_];
    __shared__ unsigned char skeep[B_][M_];
    __shared__ float smask[B_][APB_];          // assigned as float mask
    __shared__ float sreg[B_];
    __shared__ int snp[B_];
    __shared__ float pacc[TPB_ / 64][B_];

    // ---- phase 1: stage boxes + keep flags; zero accumulators ----
    if (tid < B_ * M_) {                       // 256 tasks, coalesced
        const int b = tid >> 5, m = tid & 31;
        sbox[b][m] = reinterpret_cast<const float4*>(ema_bboxes)[tid];
        const float clsm = ema_classes[tid];
        bool member = false;
        for (int n = 0; n < N_; ++n)
            member |= (clsm == annotations[b * N_ * 5 + n * 5 + 4]);
        skeep[b][m] = (m < ema_counts[b] && member) ? 1 : 0;
    }
    if (tid < B_) { sreg[tid] = 0.f; snp[tid] = 0; }
    __syncthreads();

    // ---- phase 2: assignment + smooth-L1 for owned anchors, all batches ----
    // task = b*64 + al; tasks are 64-aligned per wave -> b wave-uniform.
    for (int task = tid; task < B_ * APB_; task += TPB_) {
        const int b = task >> 6, al = task & 63;
        const int a = a0 + al;
        if (a >= A_) continue;
        const float4 anc = reinterpret_cast<const float4*>(anchors)[a];
        const float aw = anc.z - anc.x;
        const float ah = anc.w - anc.y;
        const float area_a = aw * ah;

        float best = -1.0f;
        int barg = 0;
        for (int m = 0; m < M_; ++m) {
            if (!skeep[b][m]) continue;        // wave-uniform
            const float4 bb = sbox[b][m];
            float iw = fminf(anc.z, bb.z) - fmaxf(anc.x, bb.x);
            float ih = fminf(anc.w, bb.w) - fmaxf(anc.y, bb.y);
            iw = fmaxf(iw, 0.f);
            ih = fmaxf(ih, 0.f);
            const float inter = iw * ih;
            const float areab = (bb.z - bb.x) * (bb.w - bb.y);
            const float uni = fmaxf(area_a + areab - inter, 1e-8f);
            const float iou = inter / uni;
            if (iou > best) { best = iou; barg = m; }   // strict >: first-max = jnp.argmax
        }
        const bool has = (best >= 0.0f);       // any kept box -> iou >= 0
        const bool pos = has && (best >= 0.5f);
        smask[b][al] = (has && (best < 0.4f || best >= 0.5f)) ? 1.0f : 0.0f;

        if (pos) {
            const float4 ab = sbox[b][barg];
            float gw = ab.z - ab.x;
            float gh = ab.w - ab.y;
            const float gcx = ab.x + 0.5f * gw;   // center with UNclipped w/h (ref order)
            const float gcy = ab.y + 0.5f * gh;
            gw = fmaxf(gw, 1.0f);
            gh = fmaxf(gh, 1.0f);
            const float acx = anc.x + 0.5f * aw;
            const float acy = anc.y + 0.5f * ah;
            float t[4];
            t[0] = (gcx - acx) / aw / 0.1f;
            t[1] = (gcy - acy) / ah / 0.1f;
            t[2] = __logf(gw / aw) / 0.2f;
            t[3] = __logf(gh / ah) / 0.2f;
            const float4 r = reinterpret_cast<const float4*>(regress)[b * A_ + a];
            const float rr[4] = {r.x, r.y, r.z, r.w};
            float rl = 0.f;
            for (int k = 0; k < 4; ++k) {
                const float d = fabsf(t[k] - rr[k]);
                rl += (d <= (1.0f / 9.0f)) ? 4.5f * d * d : (d - 0.5f / 9.0f);
            }
            atomicAdd(&snp[b], 1);             // LDS atomics, pos anchors are rare
            atomicAdd(&sreg[b], rl);
        }
    }
    __syncthreads();

    // ---- phase 3: classification from preloaded registers ----
    float acc[B_];
#pragma unroll
    for (int b = 0; b < B_; ++b) acc[b] = 0.f;

    if (act3) {
        float sx = 0.f, sy = 0.f, sz = 0.f, sw = 0.f;
#pragma unroll
        for (int b = 0; b < B_; ++b) {
            sx += e[b].x; sy += e[b].y; sz += e[b].z; sw += e[b].w;
        }
        // alpha_sum[a,c] = B*a0 + (a1-a0)*sum_b ema   (bug-faithful batch-sum)
        const float ax = 0.4f + 0.9f * sx;
        const float ay = 0.4f + 0.9f * sy;
        const float az = 0.4f + 0.9f * sz;
        const float aw4 = 0.4f + 0.9f * sw;
#pragma unroll
        for (int b = 0; b < B_; ++b) {
            const float mk = smask[b][al3];    // multiply-mask, no branch
            float s = cls_term(e[b].x, p[b].x, ax);
            s += cls_term(e[b].y, p[b].y, ay);
            s += cls_term(e[b].z, p[b].z, az);
            s += cls_term(e[b].w, p[b].w, aw4);
            acc[b] += mk * s;
        }
    }

    // ---- reduce: 5 waves -> LDS -> 8 writers ----
#pragma unroll
    for (int b = 0; b < B_; ++b)
        for (int off = 32; off; off >>= 1)
            acc[b] += __shfl_down(acc[b], off);
    const int wv = tid >> 6;
    if ((tid & 63) == 0) {
#pragma unroll
        for (int b = 0; b < B_; ++b) pacc[wv][b] = acc[b];
    }
    __syncthreads();
    if (tid < B_) {
        float tot = 0.f;
#pragma unroll
        for (int w = 0; w < TPB_ / 64; ++w) tot += pacc[w][tid];
        clspart[tid * NB_ + blockIdx.x] = (double)tot;
        regpart[tid * NB_ + blockIdx.x] = (double)sreg[tid];
        pospart[tid * NB_ + blockIdx.x] = snp[tid];
    }
}

// Single block, one flat phase: b = tid/32, 32 lanes stride the batch's
// partials (independent loads, latency hidden), width-32 shuffle reduce.
__global__ __launch_bounds__(256) void k_fin(
        const double* __restrict__ regpart,   // [B,NB]
        const double* __restrict__ clspart,   // [B,NB]
        const int* __restrict__ pospart,      // [B,NB]
        float* __restrict__ out)
{
    const int tid = threadIdx.x;
    const int b = tid >> 5;
    const int l = tid & 31;

    double r = 0.0, s = 0.0;
    int p = 0;
#pragma unroll
    for (int k = 0; k < NB_ / 32; ++k) {
        r += regpart[b * NB_ + l + k * 32];
        s += clspart[b * NB_ + l + k * 32];
        p += pospart[b * NB_ + l + k * 32];
    }
    for (int off = 16; off; off >>= 1) {
        r += __shfl_down(r, off, 32);
        s += __shfl_down(s, off, 32);
        p += __shfl_down(p, off, 32);
    }

    __shared__ double scls[B_], sregs[B_];
    __shared__ int snp[B_];
    if (l == 0) { scls[b] = s; sregs[b] = r; snp[b] = p; }
    __syncthreads();

    if (tid == 0) {
        double c = 0.0, rr = 0.0;
        for (int b2 = 0; b2 < B_; ++b2) {
            const int n = snp[b2];
            c += scls[b2] / (double)(n > 1 ? n : 1);
            if (n > 0) rr += sregs[b2] / (4.0 * (double)n);
        }
        out[0] = (float)(c / (double)B_);
        out[1] = (float)(rr / (double)B_);
    }
}

extern "C" void kernel_launch(void* const* d_in, const int* in_sizes, int n_in,
                              void* d_out, int out_size, void* d_ws, size_t ws_size,
                              hipStream_t stream) {
    const float* classifications     = (const float*)d_in[0];
    const float* regressions         = (const float*)d_in[1];
    const float* anchors             = (const float*)d_in[2];
    const float* ema_classifications = (const float*)d_in[3];
    const float* ema_classes         = (const float*)d_in[4];
    const float* ema_bboxes          = (const float*)d_in[5];
    const int*   ema_counts          = (const int*)d_in[6];
    const float* annotations         = (const float*)d_in[7];
    float* out = (float*)d_out;

    char* ws = (char*)d_ws;
    double* regpart = (double*)ws;                // [B_*NB_] doubles
    double* clspart = (double*)(ws + 49152);      // [B_*NB_] doubles
    int*    pospart = (int*)(ws + 98304);         // [B_*NB_] ints

    k_main<<<NB_, TPB_, 0, stream>>>(anchors, regressions, classifications,
                                     ema_classifications, ema_classes, ema_bboxes,
                                     ema_counts, annotations,
                                     regpart, clspart, pospart);

    k_fin<<<1, 256, 0, stream>>>(regpart, clspart, pospart, out);
}

// Round 6
// 120.848 us; speedup vs baseline: 1.1879x; 1.1879x over previous
//
#include <hip/hip_runtime.h>

#define B_ 8
#define A_ 49104
#define C_ 20
#define M_ 32
#define N_ 16
#define AC_ (A_ * C_)     // 982080
#define APB_ 64           // anchors per block (fused kernel)
#define NB_ 768           // blocks = ceil(A/64)
#define TPB_ 320          // 5 waves; 64 anchors * 5 float4-chunks = 320 cls tasks

// Workspace: regpart double[B][NB] @0 (49152 B), clspart double[B][NB] @49152,
//            pospart int[B][NB] @98304. 'assigned' lives in LDS only.
//
// R5 lesson (measured): preloading the 16 float4 cls-pass operands at kernel
// entry and carrying them across two __syncthreads barriers spilled to
// scratch (VGPR_Count=68 + spills, occupancy 12%, k_main 48us). The compiler
// drains vmcnt(0) at every barrier anyway, so cross-barrier load hiding is
// structurally impossible. This version issues all 16 loads INSIDE phase 3
// (no barrier crossing): one batched vmcnt group instead of R4's 8 divergent
// load-use chains.

__device__ __forceinline__ float cls_term(float e, float p, float alpha) {
    const float pc = fminf(fmaxf(p, 1e-4f), 1.0f - 1e-4f);
    const float ec = fminf(fmaxf(e, 1e-4f), 1.0f - 1e-4f);
    const float bce = -(ec * __logf(pc) + (1.0f - ec) * __logf(1.0f - pc));
    const float df = fabsf(ec - pc);
    return alpha * df * df * bce;
}

__global__ __launch_bounds__(TPB_) void k_main(
        const float* __restrict__ anchors,        // [A,4]
        const float* __restrict__ regress,        // [B,A,4]
        const float* __restrict__ cls,            // [B,A,C]
        const float* __restrict__ ema,            // [B,A,C]
        const float* __restrict__ ema_classes,    // [B,M]
        const float* __restrict__ ema_bboxes,     // [B,M,4]
        const int*   __restrict__ ema_counts,     // [B]
        const float* __restrict__ annotations,    // [B,N,5]
        double* __restrict__ regpart,             // [B,NB]
        double* __restrict__ clspart,             // [B,NB]
        int* __restrict__ pospart)                // [B,NB]
{
    const int tid = threadIdx.x;
    const int a0 = blockIdx.x * APB_;

    __shared__ float4 sbox[B_][M_];
    __shared__ unsigned char skeep[B_][M_];
    __shared__ float smask[B_][APB_];          // assigned as float mask
    __shared__ float sreg[B_];
    __shared__ int snp[B_];
    __shared__ float pacc[TPB_ / 64][B_];

    // ---- phase 1: stage boxes + keep flags; zero accumulators ----
    if (tid < B_ * M_) {                       // 256 tasks, coalesced
        const int b = tid >> 5, m = tid & 31;
        sbox[b][m] = reinterpret_cast<const float4*>(ema_bboxes)[tid];
        const float clsm = ema_classes[tid];
        bool member = false;
        for (int n = 0; n < N_; ++n)
            member |= (clsm == annotations[b * N_ * 5 + n * 5 + 4]);
        skeep[b][m] = (m < ema_counts[b] && member) ? 1 : 0;
    }
    if (tid < B_) { sreg[tid] = 0.f; snp[tid] = 0; }
    __syncthreads();

    // ---- phase 2: assignment + smooth-L1 for owned anchors, all batches ----
    // task = b*64 + al; tasks are 64-aligned per wave -> b wave-uniform.
    for (int task = tid; task < B_ * APB_; task += TPB_) {
        const int b = task >> 6, al = task & 63;
        const int a = a0 + al;
        if (a >= A_) continue;
        const float4 anc = reinterpret_cast<const float4*>(anchors)[a];
        const float aw = anc.z - anc.x;
        const float ah = anc.w - anc.y;
        const float area_a = aw * ah;

        float best = -1.0f;
        int barg = 0;
        for (int m = 0; m < M_; ++m) {
            if (!skeep[b][m]) continue;        // wave-uniform
            const float4 bb = sbox[b][m];
            float iw = fminf(anc.z, bb.z) - fmaxf(anc.x, bb.x);
            float ih = fminf(anc.w, bb.w) - fmaxf(anc.y, bb.y);
            iw = fmaxf(iw, 0.f);
            ih = fmaxf(ih, 0.f);
            const float inter = iw * ih;
            const float areab = (bb.z - bb.x) * (bb.w - bb.y);
            const float uni = fmaxf(area_a + areab - inter, 1e-8f);
            const float iou = inter / uni;
            if (iou > best) { best = iou; barg = m; }   // strict >: first-max = jnp.argmax
        }
        const bool has = (best >= 0.0f);       // any kept box -> iou >= 0
        const bool pos = has && (best >= 0.5f);
        smask[b][al] = (has && (best < 0.4f || best >= 0.5f)) ? 1.0f : 0.0f;

        if (pos) {
            const float4 ab = sbox[b][barg];
            float gw = ab.z - ab.x;
            float gh = ab.w - ab.y;
            const float gcx = ab.x + 0.5f * gw;   // center with UNclipped w/h (ref order)
            const float gcy = ab.y + 0.5f * gh;
            gw = fmaxf(gw, 1.0f);
            gh = fmaxf(gh, 1.0f);
            const float acx = anc.x + 0.5f * aw;
            const float acy = anc.y + 0.5f * ah;
            float t[4];
            t[0] = (gcx - acx) / aw / 0.1f;
            t[1] = (gcy - acy) / ah / 0.1f;
            t[2] = __logf(gw / aw) / 0.2f;
            t[3] = __logf(gh / ah) / 0.2f;
            const float4 r = reinterpret_cast<const float4*>(regress)[b * A_ + a];
            const float rr[4] = {r.x, r.y, r.z, r.w};
            float rl = 0.f;
            for (int k = 0; k < 4; ++k) {
                const float d = fabsf(t[k] - rr[k]);
                rl += (d <= (1.0f / 9.0f)) ? 4.5f * d * d : (d - 0.5f / 9.0f);
            }
            atomicAdd(&snp[b], 1);             // LDS atomics, pos anchors are rare
            atomicAdd(&sreg[b], rl);
        }
    }
    __syncthreads();

    // ---- phase 3: classification; all 16 loads issued unconditionally ----
    // thread t -> anchor a0 + t/5, float4 chunk t%5: contiguous 16B/lane.
    const int al3 = tid / 5;
    const int ch  = tid % 5;
    const int a3  = a0 + al3;
    float acc[B_];
#pragma unroll
    for (int b = 0; b < B_; ++b) acc[b] = 0.f;

    if (a3 < A_) {
        const size_t cell = (size_t)a3 * C_ + ch * 4;
        float4 e[B_], p[B_];
#pragma unroll
        for (int b = 0; b < B_; ++b) {
            e[b] = *reinterpret_cast<const float4*>(ema + (size_t)b * AC_ + cell);
            p[b] = *reinterpret_cast<const float4*>(cls + (size_t)b * AC_ + cell);
        }
        float sx = 0.f, sy = 0.f, sz = 0.f, sw = 0.f;
#pragma unroll
        for (int b = 0; b < B_; ++b) {
            sx += e[b].x; sy += e[b].y; sz += e[b].z; sw += e[b].w;
        }
        // alpha_sum[a,c] = B*a0 + (a1-a0)*sum_b ema   (bug-faithful batch-sum)
        const float ax = 0.4f + 0.9f * sx;
        const float ay = 0.4f + 0.9f * sy;
        const float az = 0.4f + 0.9f * sz;
        const float aw4 = 0.4f + 0.9f * sw;
#pragma unroll
        for (int b = 0; b < B_; ++b) {
            const float mk = smask[b][al3];    // multiply-mask, no branch
            float s = cls_term(e[b].x, p[b].x, ax);
            s += cls_term(e[b].y, p[b].y, ay);
            s += cls_term(e[b].z, p[b].z, az);
            s += cls_term(e[b].w, p[b].w, aw4);
            acc[b] += mk * s;
        }
    }

    // ---- reduce: 5 waves -> LDS -> 8 writers ----
#pragma unroll
    for (int b = 0; b < B_; ++b)
        for (int off = 32; off; off >>= 1)
            acc[b] += __shfl_down(acc[b], off);
    const int wv = tid >> 6;
    if ((tid & 63) == 0) {
#pragma unroll
        for (int b = 0; b < B_; ++b) pacc[wv][b] = acc[b];
    }
    __syncthreads();
    if (tid < B_) {
        float tot = 0.f;
#pragma unroll
        for (int w = 0; w < TPB_ / 64; ++w) tot += pacc[w][tid];
        clspart[tid * NB_ + blockIdx.x] = (double)tot;
        regpart[tid * NB_ + blockIdx.x] = (double)sreg[tid];
        pospart[tid * NB_ + blockIdx.x] = snp[tid];
    }
}

// Single block, one flat phase: b = tid/32, 32 lanes stride the batch's
// partials (independent loads, latency hidden), width-32 shuffle reduce.
__global__ __launch_bounds__(256) void k_fin(
        const double* __restrict__ regpart,   // [B,NB]
        const double* __restrict__ clspart,   // [B,NB]
        const int* __restrict__ pospart,      // [B,NB]
        float* __restrict__ out)
{
    const int tid = threadIdx.x;
    const int b = tid >> 5;
    const int l = tid & 31;

    double r = 0.0, s = 0.0;
    int p = 0;
#pragma unroll
    for (int k = 0; k < NB_ / 32; ++k) {
        r += regpart[b * NB_ + l + k * 32];
        s += clspart[b * NB_ + l + k * 32];
        p += pospart[b * NB_ + l + k * 32];
    }
    for (int off = 16; off; off >>= 1) {
        r += __shfl_down(r, off, 32);
        s += __shfl_down(s, off, 32);
        p += __shfl_down(p, off, 32);
    }

    __shared__ double scls[B_], sregs[B_];
    __shared__ int snp[B_];
    if (l == 0) { scls[b] = s; sregs[b] = r; snp[b] = p; }
    __syncthreads();

    if (tid == 0) {
        double c = 0.0, rr = 0.0;
        for (int b2 = 0; b2 < B_; ++b2) {
            const int n = snp[b2];
            c += scls[b2] / (double)(n > 1 ? n : 1);
            if (n > 0) rr += sregs[b2] / (4.0 * (double)n);
        }
        out[0] = (float)(c / (double)B_);
        out[1] = (float)(rr / (double)B_);
    }
}

extern "C" void kernel_launch(void* const* d_in, const int* in_sizes, int n_in,
                              void* d_out, int out_size, void* d_ws, size_t ws_size,
                              hipStream_t stream) {
    const float* classifications     = (const float*)d_in[0];
    const float* regressions         = (const float*)d_in[1];
    const float* anchors             = (const float*)d_in[2];
    const float* ema_classifications = (const float*)d_in[3];
    const float* ema_classes         = (const float*)d_in[4];
    const float* ema_bboxes          = (const float*)d_in[5];
    const int*   ema_counts          = (const int*)d_in[6];
    const float* annotations         = (const float*)d_in[7];
    float* out = (float*)d_out;

    char* ws = (char*)d_ws;
    double* regpart = (double*)ws;                // [B_*NB_] doubles
    double* clspart = (double*)(ws + 49152);      // [B_*NB_] doubles
    int*    pospart = (int*)(ws + 98304);         // [B_*NB_] ints

    k_main<<<NB_, TPB_, 0, stream>>>(anchors, regressions, classifications,
                                     ema_classifications, ema_classes, ema_bboxes,
                                     ema_counts, annotations,
                                     regpart, clspart, pospart);

    k_fin<<<1, 256, 0, stream>>>(regpart, clspart, pospart, out);
}